// Round 14
// baseline (1279.990 us; speedup 1.0000x reference)
//
#include <hip/hip_runtime.h>
#include <stdint.h>

#define B_ 128
#define T_ 1024
#define BT_ (B_*T_)
#define H_ 64
#define G_ 192
#define PL_ 432
#define NP_ 5
#define FUSED_ 288
#define N_IN 41

typedef unsigned short u16;
typedef __attribute__((ext_vector_type(8))) short bf16x8;
typedef __attribute__((ext_vector_type(4))) float f32x4;
typedef _Float16 h2 __attribute__((ext_vector_type(2)));
typedef _Float16 h8 __attribute__((ext_vector_type(8)));

__device__ inline float bf2f(u16 u){ union{float f; unsigned int i;} c; c.i = ((unsigned int)u)<<16; return c.f; }
__device__ inline u16 f2bf(float f){ unsigned int u = __float_as_uint(f); unsigned int r = (u + 0x7fffu + ((u>>16)&1u))>>16; return (u16)r; }
__device__ inline _Float16 bf2h(u16 u){ return (_Float16)bf2f(u); }
__device__ inline float sigm(float x){ return 1.f/(1.f+__expf(-x)); }
__device__ inline float tanh_(float x){ float t = __expf(fminf(fmaxf(2.f*x,-30.f),30.f)); return (t-1.f)/(t+1.f); }
// short-chain variants for the recur critical path:
__device__ inline float sigm_f(float x){ return 1.f/(1.f+__expf(-x)); }
__device__ inline float tanh_f(float x){ return 2.f/(1.f+__expf(-2.f*x)) - 1.f; }  // saturates via exp->inf->rcp->0
__device__ inline float gelu_(float x){ return 0.5f*x*(1.f + erff(x*0.70710678118654752f)); }
__device__ inline float wredsum(float v){
  #pragma unroll
  for(int o=32;o>0;o>>=1) v += __shfl_xor(v,o);
  return v;
}

#if __has_builtin(__builtin_amdgcn_fdot2)
__device__ inline float dot2(h2 a, h2 b, float c){ return __builtin_amdgcn_fdot2(a, b, c, false); }
#else
__device__ inline float dot2(h2 a, h2 b, float c){ return c + (float)a.x*(float)b.x + (float)a.y*(float)b.y; }
#endif

// ---------------- input canonicalization: anything -> bf16 in ws ----------------
struct CvtArgs {
  const void* src[N_IN];
  unsigned dstOff[N_IN];
  unsigned cnt[N_IN];
  unsigned blkStart[N_IN+1];
};

__global__ __launch_bounds__(256) void convert_k(CvtArgs a, u16* __restrict__ dst){
  const bool isbf = (((const u16*)a.src[21])[0] == 0x3F80u);
  int b = blockIdx.x;
  int lo = 0, hi = N_IN;
  while (hi - lo > 1){ int mid = (lo+hi)>>1; if (a.blkStart[mid] <= (unsigned)b) lo = mid; else hi = mid; }
  const int i = lo;
  const unsigned lb = (unsigned)b - a.blkStart[i];
  const unsigned n = a.cnt[i];
  u16* d = dst + a.dstOff[i];
  if (isbf){
    const u16* s = (const u16*)a.src[i];
    #pragma unroll
    for(int e=0;e<8;e++){ unsigned idx = lb*2048u + e*256u + threadIdx.x; if (idx < n) d[idx] = s[idx]; }
  } else {
    const float* s = (const float*)a.src[i];
    #pragma unroll
    for(int e=0;e<8;e++){ unsigned idx = lb*2048u + e*256u + threadIdx.x; if (idx < n) d[idx] = f2bf(s[idx]); }
  }
}

// ---------------- gi = A @ [Wf;Wb]^T + [bf;bb]  (bf16 MFMA GEMM) ----------------
template<int K>
__global__ __launch_bounds__(256) void gi_gemm(const u16* __restrict__ A,
    const u16* __restrict__ Wf, const u16* __restrict__ Wb,
    const u16* __restrict__ biasF, const u16* __restrict__ biasB,
    u16* __restrict__ out)
{
  const int wv = threadIdx.x >> 6, lane = threadIdx.x & 63;
  const int l15 = lane & 15, quad = lane >> 4;
  const size_t mBase = (size_t)blockIdx.x*64 + wv*16;

  bf16x8 afr[K/32];
  #pragma unroll
  for(int kc=0;kc<K/32;kc++)
    afr[kc] = *(const bf16x8*)(A + (mBase + l15)*K + kc*32 + quad*8);

  #pragma unroll
  for(int half=0; half<2; ++half){
    const u16* W    = half ? Wb : Wf;
    const u16* bias = half ? biasB : biasF;
    u16* o = out + (size_t)half * BT_ * G_;
    for(int nt=0; nt<12; ++nt){
      int n = nt*16 + l15;
      f32x4 acc = {0.f,0.f,0.f,0.f};
      #pragma unroll
      for(int kc=0;kc<K/32;kc++){
        bf16x8 bfr = *(const bf16x8*)(W + n*K + kc*32 + quad*8);
        acc = __builtin_amdgcn_mfma_f32_16x16x32_bf16(afr[kc], bfr, acc, 0,0,0);
      }
      float bv = bf2f(bias[n]);
      #pragma unroll
      for(int r=0;r<4;r++){
        size_t row = mBase + quad*4 + r;
        o[row*G_ + n] = f2bf(acc[r] + bv);
      }
    }
  }
}

// ---------------- GRU recurrence: ONE WAVE per (dir, b) chain ----------------
// R9/R13 structure (replicated best: 473us/dispatch) with a shortened
// post-matvec critical path: gi gate values folded into dot2 accumulator
// seeds, tanh via 2*sigmoid(2x)-1 (no clamp), h update as one fma.
// 256 blocks x 64 threads = 1 wave/CU; 96 f16-pair weights in VGPRs
// (waves_per_eu(1,1) -> VGPR_Count 132, no spill); gi staged global->LDS
// in 16-step chunks via async global_load_lds (one vmcnt(0) per 16 steps);
// barrier-free via single-wave lockstep + in-order DS.
__global__ __launch_bounds__(64)
__attribute__((amdgpu_waves_per_eu(1,1)))
void recur(const u16* __restrict__ gi,
    const u16* __restrict__ WhF, const u16* __restrict__ WhB,
    const u16* __restrict__ bhF, const u16* __restrict__ bhB,
    u16* __restrict__ y_x1, float* __restrict__ hfin, int layer)
{
  const int chain = blockIdx.x;
  const int dir = chain >> 7;
  const int b = chain & 127;
  const int j = threadIdx.x;           // lane 0..63
  const u16* Wh = dir ? WhB : WhF;
  const u16* bh = dir ? bhB : bhF;

  // this lane's three Whh rows as packed f16 pairs (bf16->f16 is exact)
  h2 wr[32], wz[32], wn[32];
  #pragma unroll
  for(int k8=0;k8<8;k8++){
    uint4 q;
    q = *(const uint4*)(Wh + (size_t)j*64 + k8*8);
    wr[4*k8+0] = (h2){bf2h((u16)(q.x&0xffffu)), bf2h((u16)(q.x>>16))};
    wr[4*k8+1] = (h2){bf2h((u16)(q.y&0xffffu)), bf2h((u16)(q.y>>16))};
    wr[4*k8+2] = (h2){bf2h((u16)(q.z&0xffffu)), bf2h((u16)(q.z>>16))};
    wr[4*k8+3] = (h2){bf2h((u16)(q.w&0xffffu)), bf2h((u16)(q.w>>16))};
    q = *(const uint4*)(Wh + (size_t)(64+j)*64 + k8*8);
    wz[4*k8+0] = (h2){bf2h((u16)(q.x&0xffffu)), bf2h((u16)(q.x>>16))};
    wz[4*k8+1] = (h2){bf2h((u16)(q.y&0xffffu)), bf2h((u16)(q.y>>16))};
    wz[4*k8+2] = (h2){bf2h((u16)(q.z&0xffffu)), bf2h((u16)(q.z>>16))};
    wz[4*k8+3] = (h2){bf2h((u16)(q.w&0xffffu)), bf2h((u16)(q.w>>16))};
    q = *(const uint4*)(Wh + (size_t)(128+j)*64 + k8*8);
    wn[4*k8+0] = (h2){bf2h((u16)(q.x&0xffffu)), bf2h((u16)(q.x>>16))};
    wn[4*k8+1] = (h2){bf2h((u16)(q.y&0xffffu)), bf2h((u16)(q.y>>16))};
    wn[4*k8+2] = (h2){bf2h((u16)(q.z&0xffffu)), bf2h((u16)(q.z>>16))};
    wn[4*k8+3] = (h2){bf2h((u16)(q.w&0xffffu)), bf2h((u16)(q.w>>16))};
  }
  const float bhr = bf2f(bh[j]), bhz = bf2f(bh[64+j]), bhn = bf2f(bh[128+j]);

  __shared__ __align__(16) u16 giLds[2][3072];   // 2 x 16 steps x 192 u16
  __shared__ _Float16 hSf[64];
  h8* hS8 = (h8*)hSf;
  hSf[j] = (_Float16)0.f;              // in-order DS: visible to the loop's reads

  const u16* giC = gi + (size_t)chain * T_ * G_;

  // async chunk DMA: 16 rows (6144 B) as 6 x (64 lanes x 16 B)
  auto issue_chunk = [&](int c, int buf){
    int tbase = dir ? (1008 - c*16) : (c*16);
    const u16* src = giC + (size_t)tbase*G_ + j*8;
    u16* dst = &giLds[buf][0];
    #pragma unroll
    for(int i=0;i<6;i++){
      __builtin_amdgcn_global_load_lds(
        (const __attribute__((address_space(1))) void*)(src + i*512),
        (__attribute__((address_space(3))) void*)(dst + i*512), 16, 0, 0);
    }
  };

  issue_chunk(0, 0);

  float h = 0.f;
  for(int c=0; c<64; ++c){
    asm volatile("s_waitcnt vmcnt(0)" ::: "memory");  // chunk c landed in LDS
    if (c < 63) issue_chunk(c+1, (c+1)&1);
    const u16* gbuf = &giLds[c&1][0];
    #pragma unroll 2
    for(int ls=0; ls<16; ++ls){
      int row = dir ? (15-ls) : ls;
      const u16* rowp = gbuf + row*G_;
      // gi gate values (h-independent): fold r/z into accumulator seeds
      float gr = bf2f(rowp[j]), gz = bf2f(rowp[64+j]), gn = bf2f(rowp[128+j]);
      // matvec: 96 dot2 ops, 2 f32 accumulators per gate
      float r0=bhr+gr, r1=0.f, z0=bhz+gz, z1=0.f, n0=bhn, n1=0.f;
      #pragma unroll
      for(int k=0;k<8;k++){
        h8 hv = hS8[k];
        h2 p0 = __builtin_shufflevector(hv, hv, 0, 1);
        h2 p1 = __builtin_shufflevector(hv, hv, 2, 3);
        h2 p2 = __builtin_shufflevector(hv, hv, 4, 5);
        h2 p3 = __builtin_shufflevector(hv, hv, 6, 7);
        r0 = dot2(wr[4*k+0], p0, r0); r1 = dot2(wr[4*k+1], p1, r1);
        r0 = dot2(wr[4*k+2], p2, r0); r1 = dot2(wr[4*k+3], p3, r1);
        z0 = dot2(wz[4*k+0], p0, z0); z1 = dot2(wz[4*k+1], p1, z1);
        z0 = dot2(wz[4*k+2], p2, z0); z1 = dot2(wz[4*k+3], p3, z1);
        n0 = dot2(wn[4*k+0], p0, n0); n1 = dot2(wn[4*k+1], p1, n1);
        n0 = dot2(wn[4*k+2], p2, n0); n1 = dot2(wn[4*k+3], p3, n1);
      }

      float r  = sigm_f(r0 + r1);
      float z  = sigm_f(z0 + z1);
      float nn = tanh_f(fmaf(r, n0 + n1, gn));
      h = fmaf(z, h - nn, nn);         // (1-z)*nn + z*h

      hSf[j] = (_Float16)h;            // in-order DS; next iter's reads see it

      if (layer == 0){
        int s = c*16 + ls;
        int t = dir ? (T_-1-s) : s;
        y_x1[((size_t)b*T_ + t)*128 + dir*64 + j] = f2bf(h);
      }
    }
  }
  if (layer == 1) hfin[b*FUSED_ + dir*64 + j] = h;
}

// ---------------- fused static branch + qkv (gates stay in LDS) ----------------
__global__ __launch_bounds__(448) void staticqkv_k(const u16* __restrict__ sx,
   const u16* __restrict__ smW, const u16* __restrict__ smb,
   const u16* __restrict__ lng, const u16* __restrict__ lnb,
   const u16* __restrict__ gW, const u16* __restrict__ gb,
   const u16* __restrict__ phys, const u16* __restrict__ aW,
   const u16* __restrict__ ab,
   float* __restrict__ fused, float* __restrict__ qkv)
{
  int b = blockIdx.x, tid = threadIdx.x;
  __shared__ float gS[5];
  if (tid < 64){
    int j = tid;
    float xr[16];
    #pragma unroll
    for(int k=0;k<16;k++) xr[k] = bf2f(sx[b*16+k]);
    float acc = bf2f(smb[j]);
    #pragma unroll
    for(int k=0;k<16;k++) acc += xr[k]*bf2f(smW[j*16+k]);
    float xg = gelu_(acc);
    float m = wredsum(xg)*(1.f/64.f);
    float d = xg - m;
    float v = wredsum(d*d)*(1.f/64.f);
    float se = d*rsqrtf(v+1e-5f)*bf2f(lng[j]) + bf2f(lnb[j]);
    fused[b*FUSED_ + 128 + j] = se;
    #pragma unroll
    for(int i=0;i<5;i++){
      float p = se*bf2f(gW[i*64+j]);
      float s = wredsum(p);
      if (j == 0) gS[i] = sigm(s + bf2f(gb[i]));
    }
  }
  __syncthreads();
  int l = tid;
  if (l < PL_){
    float pv[5];
    #pragma unroll
    for(int i=0;i<5;i++) pv[i] = bf2f(phys[((size_t)b*5+i)*PL_ + l]) * gS[i];
    #pragma unroll
    for(int c=0;c<15;c++){
      float a = bf2f(ab[c]);
      #pragma unroll
      for(int i=0;i<5;i++) a += pv[i]*bf2f(aW[c*5+i]);
      qkv[((size_t)b*15+c)*PL_ + l] = a;
    }
  }
}

// ---------------- attention (rank-1 scores, softmax over j) ----------------
__global__ __launch_bounds__(256) void attn_k(const float* __restrict__ qkv,
                                              float* __restrict__ ao)
{
  int h = blockIdx.x, b = blockIdx.y;
  int tid = threadIdx.x;
  __shared__ float kS[PL_], vS[PL_];
  __shared__ float red[32];
  const float* qb = qkv + ((size_t)b*15 + h)*PL_;
  const float* kb = qkv + ((size_t)b*15 + 5 + h)*PL_;
  const float* vb = qkv + ((size_t)b*15 + 10 + h)*PL_;
  for(int j=tid;j<PL_;j+=256){ kS[j]=kb[j]; vS[j]=vb[j]; }
  __syncthreads();
  float lmax=-1e30f, lmin=1e30f;
  for(int j=tid;j<PL_;j+=256){ float kv=kS[j]; lmax=fmaxf(lmax,kv); lmin=fminf(lmin,kv); }
  #pragma unroll
  for(int o=32;o>0;o>>=1){ lmax=fmaxf(lmax,__shfl_xor(lmax,o)); lmin=fminf(lmin,__shfl_xor(lmin,o)); }
  int wv = tid>>6;
  if ((tid&63)==0){ red[wv]=lmax; red[8+wv]=lmin; }
  __syncthreads();
  if (tid==0){
    float mx=red[0], mn=red[8];
    for(int i=1;i<4;i++){ mx=fmaxf(mx,red[i]); mn=fminf(mn,red[8+i]); }
    red[16]=mx; red[17]=mn;
  }
  __syncthreads();
  float kmx=red[16], kmn=red[17];
  for(int i=tid;i<PL_;i+=256){
    float s = qb[i];
    float m = fmaxf(s*kmx, s*kmn);
    float den=0.f, num=0.f;
    #pragma unroll 4
    for(int j=0;j<PL_;j++){
      float e = __expf(s*kS[j]-m);
      den += e; num += e*vS[j];
    }
    ao[((size_t)b*PL_+i)*5 + h] = num/den;
  }
}

// ---------------- fused output projection + dilated convs (p2 stays in LDS) ----------------
template<int KS, int DIL, int PAD>
__device__ inline void do_conv(const float* pS, const u16* Wc, const u16* bc,
                               float* fused, int b, int o, int p, int cslot)
{
  const int Lout = PL_ + 2*PAD - DIL*(KS-1);
  float w[5][KS];
  #pragma unroll
  for(int i=0;i<5;i++)
    #pragma unroll
    for(int t=0;t<KS;t++) w[i][t] = bf2f(Wc[(o*5+i)*KS + t]);
  float bias = bf2f(bc[o]);
  float acc = 0.f;
  for(int l=p; l<Lout; l+=8){
    float s = bias;
    #pragma unroll
    for(int t=0;t<KS;t++){
      int idx = l - PAD + t*DIL;
      if (idx >= 0 && idx < PL_){
        #pragma unroll
        for(int i=0;i<5;i++) s += w[i][t]*pS[i*PL_ + idx];
      }
    }
    acc += gelu_(s);
  }
  #pragma unroll
  for(int off=1;off<8;off<<=1) acc += __shfl_xor(acc,off);
  if (p == 0) fused[b*FUSED_ + 192 + cslot*32 + o] = acc/(float)Lout;
}

__global__ __launch_bounds__(256) void projconv_k(const float* __restrict__ ao,
  const u16* __restrict__ oW, const u16* __restrict__ ob,
  const u16* __restrict__ W1c, const u16* __restrict__ b1c,
  const u16* __restrict__ W2c, const u16* __restrict__ b2c,
  const u16* __restrict__ W3c, const u16* __restrict__ b3c,
  float* __restrict__ fused)
{
  int b = blockIdx.x, tid = threadIdx.x;
  __shared__ float pS[5*PL_];
  for(int l=tid; l<PL_; l+=256){
    float a[5];
    #pragma unroll
    for(int hh=0;hh<5;hh++) a[hh] = ao[((size_t)b*PL_+l)*5 + hh];
    #pragma unroll
    for(int c=0;c<5;c++){
      float s = bf2f(ob[c]);
      #pragma unroll
      for(int hh=0;hh<5;hh++) s += a[hh]*bf2f(oW[c*5+hh]);
      pS[c*PL_ + l] = s;
    }
  }
  __syncthreads();
  int o = tid >> 3, p = tid & 7;
  do_conv<3,1,1>(pS, W1c, b1c, fused, b, o, p, 0);
  do_conv<5,2,2>(pS, W2c, b2c, fused, b, o, p, 1);
  do_conv<9,4,4>(pS, W3c, b3c, fused, b, o, p, 2);
}

// ---------------- head: LN + MLP (output dtype adaptive) ----------------
__global__ __launch_bounds__(448) void head_k(const float* __restrict__ fused,
   const u16* __restrict__ lng, const u16* __restrict__ lnb,
   const u16* __restrict__ W1, const u16* __restrict__ b1,
   const u16* __restrict__ W2, const u16* __restrict__ b2,
   void* __restrict__ out, const u16* __restrict__ detect)
{
  const bool isbf = (detect[0] == 0x3F80u);
  int b = blockIdx.x, tid = threadIdx.x;
  __shared__ float fS[FUSED_];
  __shared__ float hS[128];
  __shared__ float red[32];
  float v = (tid < FUSED_) ? fused[b*FUSED_ + tid] : 0.f;
  float s1 = wredsum(v);
  float s2 = wredsum(v*v);
  int wv = tid>>6;
  if ((tid&63)==0){ red[wv]=s1; red[8+wv]=s2; }
  __syncthreads();
  if (tid==0){
    float S=0.f, SS=0.f;
    for(int i=0;i<7;i++){ S+=red[i]; SS+=red[8+i]; }
    float m = S/288.f;
    red[16]=m; red[17]=SS/288.f - m*m;
  }
  __syncthreads();
  float m = red[16], var = red[17];
  if (tid < FUSED_) fS[tid] = (v-m)*rsqrtf(var+1e-5f)*bf2f(lng[tid]) + bf2f(lnb[tid]);
  __syncthreads();
  if (tid < 128){
    float a = bf2f(b1[tid]);
    const u16* wr = W1 + (size_t)tid*FUSED_;
    #pragma unroll
    for(int k8=0;k8<36;k8++){
      uint4 q = *(const uint4*)(wr + k8*8);
      a += fS[8*k8+0]*bf2f((u16)(q.x&0xffffu)) + fS[8*k8+1]*bf2f((u16)(q.x>>16))
         + fS[8*k8+2]*bf2f((u16)(q.y&0xffffu)) + fS[8*k8+3]*bf2f((u16)(q.y>>16))
         + fS[8*k8+4]*bf2f((u16)(q.z&0xffffu)) + fS[8*k8+5]*bf2f((u16)(q.z>>16))
         + fS[8*k8+6]*bf2f((u16)(q.w&0xffffu)) + fS[8*k8+7]*bf2f((u16)(q.w>>16));
    }
    hS[tid] = gelu_(a);
  }
  __syncthreads();
  if (tid < PL_){
    float a = bf2f(b2[tid]);
    const u16* wr = W2 + (size_t)tid*128;
    #pragma unroll
    for(int k8=0;k8<16;k8++){
      uint4 q = *(const uint4*)(wr + k8*8);
      a += hS[8*k8+0]*bf2f((u16)(q.x&0xffffu)) + hS[8*k8+1]*bf2f((u16)(q.x>>16))
         + hS[8*k8+2]*bf2f((u16)(q.y&0xffffu)) + hS[8*k8+3]*bf2f((u16)(q.y>>16))
         + hS[8*k8+4]*bf2f((u16)(q.z&0xffffu)) + hS[8*k8+5]*bf2f((u16)(q.z>>16))
         + hS[8*k8+6]*bf2f((u16)(q.w&0xffffu)) + hS[8*k8+7]*bf2f((u16)(q.w>>16));
    }
    size_t oi = (size_t)b*PL_ + tid;
    if (isbf) ((u16*)out)[oi] = f2bf(a);
    else      ((float*)out)[oi] = a;
  }
}

extern "C" void kernel_launch(void* const* d_in, const int* in_sizes, int n_in,
                              void* d_out, int out_size, void* d_ws, size_t ws_size,
                              hipStream_t stream)
{
  static const unsigned cnts[N_IN] = {
    4194304, 2048, 276480,
    6144, 12288, 192, 192,
    6144, 12288, 192, 192,
    24576, 12288, 192, 192,
    24576, 12288, 192, 192,
    1024, 64, 64, 64,
    320, 5,
    75, 15,
    25, 5,
    480, 32, 800, 32, 1440, 32,
    288, 288,
    36864, 128, 55296, 432
  };

  char* ws = (char*)d_ws;
  size_t off = 0;
  auto alloc = [&](size_t bytes){ size_t o = off; off = (off + bytes + 255) & ~(size_t)255; return o; };

  CvtArgs ca;
  const u16* cin[N_IN];
  unsigned totalBlocks = 0;
  for (int i=0;i<N_IN;i++){
    ca.src[i] = d_in[i];
    ca.cnt[i] = cnts[i];
    size_t o = alloc((size_t)cnts[i]*2);
    ca.dstOff[i] = (unsigned)(o/2);
    cin[i] = (const u16*)(ws + o);
    ca.blkStart[i] = totalBlocks;
    totalBlocks += (cnts[i] + 2047u)/2048u;
  }
  ca.blkStart[N_IN] = totalBlocks;
  u16* canon = (u16*)ws;

  u16*   gi    = (u16*)  (ws + alloc((size_t)2*BT_*G_*2));
  u16*   x1    = (u16*)  (ws + alloc((size_t)BT_*128*2));
  float* fused = (float*)(ws + alloc((size_t)B_*FUSED_*4));
  float* qkv   = (float*)(ws + alloc((size_t)B_*15*PL_*4));
  float* ao    = (float*)(ws + alloc((size_t)B_*PL_*5*4));
  (void)ws_size; (void)in_sizes; (void)n_in; (void)out_size;

  convert_k<<<totalBlocks, 256, 0, stream>>>(ca, canon);

  gi_gemm<32><<<BT_/64, 256, 0, stream>>>(cin[0], cin[3], cin[7], cin[5], cin[9], gi);
  recur<<<256, 64, 0, stream>>>(gi, cin[4], cin[8], cin[6], cin[10], x1, nullptr, 0);
  gi_gemm<128><<<BT_/64, 256, 0, stream>>>(x1, cin[11], cin[15], cin[13], cin[17], gi);
  recur<<<256, 64, 0, stream>>>(gi, cin[12], cin[16], cin[14], cin[18], nullptr, fused, 1);
  staticqkv_k<<<128, 448, 0, stream>>>(cin[1], cin[19], cin[20], cin[21], cin[22],
                                       cin[23], cin[24], cin[2], cin[25], cin[26],
                                       fused, qkv);
  attn_k<<<dim3(5,128), 256, 0, stream>>>(qkv, ao);
  projconv_k<<<128, 256, 0, stream>>>(ao, cin[27], cin[28], cin[29], cin[30],
                                      cin[31], cin[32], cin[33], cin[34], fused);
  head_k<<<128, 448, 0, stream>>>(fused, cin[35], cin[36], cin[37], cin[38], cin[39], cin[40],
                                  d_out, (const u16*)d_in[21]);
}

// Round 15
// 1252.802 us; speedup vs baseline: 1.0217x; 1.0217x over previous
//
#include <hip/hip_runtime.h>
#include <stdint.h>

#define B_ 128
#define T_ 1024
#define BT_ (B_*T_)
#define H_ 64
#define G_ 192
#define PL_ 432
#define NP_ 5
#define FUSED_ 288
#define N_IN 41

typedef unsigned short u16;
typedef __attribute__((ext_vector_type(8))) short bf16x8;
typedef __attribute__((ext_vector_type(4))) float f32x4;
typedef _Float16 h2 __attribute__((ext_vector_type(2)));
typedef _Float16 h8 __attribute__((ext_vector_type(8)));

__device__ inline float bf2f(u16 u){ union{float f; unsigned int i;} c; c.i = ((unsigned int)u)<<16; return c.f; }
__device__ inline u16 f2bf(float f){ unsigned int u = __float_as_uint(f); unsigned int r = (u + 0x7fffu + ((u>>16)&1u))>>16; return (u16)r; }
__device__ inline _Float16 bf2h(u16 u){ return (_Float16)bf2f(u); }
__device__ inline float sigm(float x){ return 1.f/(1.f+__expf(-x)); }
__device__ inline float tanh_(float x){ float t = __expf(fminf(fmaxf(2.f*x,-30.f),30.f)); return (t-1.f)/(t+1.f); }
__device__ inline float gelu_(float x){ return 0.5f*x*(1.f + erff(x*0.70710678118654752f)); }
__device__ inline float wredsum(float v){
  #pragma unroll
  for(int o=32;o>0;o>>=1) v += __shfl_xor(v,o);
  return v;
}

#if __has_builtin(__builtin_amdgcn_fdot2)
__device__ inline float dot2(h2 a, h2 b, float c){ return __builtin_amdgcn_fdot2(a, b, c, false); }
#else
__device__ inline float dot2(h2 a, h2 b, float c){ return c + (float)a.x*(float)b.x + (float)a.y*(float)b.y; }
#endif

// ---------------- input canonicalization: anything -> bf16 in ws ----------------
struct CvtArgs {
  const void* src[N_IN];
  unsigned dstOff[N_IN];
  unsigned cnt[N_IN];
  unsigned blkStart[N_IN+1];
};

__global__ __launch_bounds__(256) void convert_k(CvtArgs a, u16* __restrict__ dst){
  const bool isbf = (((const u16*)a.src[21])[0] == 0x3F80u);
  int b = blockIdx.x;
  int lo = 0, hi = N_IN;
  while (hi - lo > 1){ int mid = (lo+hi)>>1; if (a.blkStart[mid] <= (unsigned)b) lo = mid; else hi = mid; }
  const int i = lo;
  const unsigned lb = (unsigned)b - a.blkStart[i];
  const unsigned n = a.cnt[i];
  u16* d = dst + a.dstOff[i];
  if (isbf){
    const u16* s = (const u16*)a.src[i];
    #pragma unroll
    for(int e=0;e<8;e++){ unsigned idx = lb*2048u + e*256u + threadIdx.x; if (idx < n) d[idx] = s[idx]; }
  } else {
    const float* s = (const float*)a.src[i];
    #pragma unroll
    for(int e=0;e<8;e++){ unsigned idx = lb*2048u + e*256u + threadIdx.x; if (idx < n) d[idx] = f2bf(s[idx]); }
  }
}

// ---------------- gi = A @ [Wf;Wb]^T + [bf;bb]  (bf16 MFMA GEMM) ----------------
template<int K>
__global__ __launch_bounds__(256) void gi_gemm(const u16* __restrict__ A,
    const u16* __restrict__ Wf, const u16* __restrict__ Wb,
    const u16* __restrict__ biasF, const u16* __restrict__ biasB,
    u16* __restrict__ out)
{
  const int wv = threadIdx.x >> 6, lane = threadIdx.x & 63;
  const int l15 = lane & 15, quad = lane >> 4;
  const size_t mBase = (size_t)blockIdx.x*64 + wv*16;

  bf16x8 afr[K/32];
  #pragma unroll
  for(int kc=0;kc<K/32;kc++)
    afr[kc] = *(const bf16x8*)(A + (mBase + l15)*K + kc*32 + quad*8);

  #pragma unroll
  for(int half=0; half<2; ++half){
    const u16* W    = half ? Wb : Wf;
    const u16* bias = half ? biasB : biasF;
    u16* o = out + (size_t)half * BT_ * G_;
    for(int nt=0; nt<12; ++nt){
      int n = nt*16 + l15;
      f32x4 acc = {0.f,0.f,0.f,0.f};
      #pragma unroll
      for(int kc=0;kc<K/32;kc++){
        bf16x8 bfr = *(const bf16x8*)(W + n*K + kc*32 + quad*8);
        acc = __builtin_amdgcn_mfma_f32_16x16x32_bf16(afr[kc], bfr, acc, 0,0,0);
      }
      float bv = bf2f(bias[n]);
      #pragma unroll
      for(int r=0;r<4;r++){
        size_t row = mBase + quad*4 + r;
        o[row*G_ + n] = f2bf(acc[r] + bv);
      }
    }
  }
}

// ---------------- GRU recurrence: ONE WAVE per (dir, b) chain ----------------
// R13-exact (best measured: 473us/dispatch, reproduced across R9/R13).
// 256 blocks x 64 threads = 1 wave/CU. Lane j owns rows j (r), 64+j (z),
// 128+j (n) of Whh as packed f16 pairs (96 VGPRs, VGPR_Count=132, no spill
// thanks to waves_per_eu(1,1)). gi staged global->LDS in 16-step chunks via
// async global_load_lds (6 x 1KB DMA, double-buffered, ONE vmcnt(0) per 16
// steps). Matvec = 96 v_dot2_f32_f16. No barriers: single-wave lockstep +
// in-order DS. 14 rounds of component isolation (R8 global latency, R9
// spill, R10/R11 wave-parallel+barrier, R12 MFMA, R14 activation chain) all
// converge here: the ~1150cyc/step is the serial LDS-RAW + in-order-DS +
// dependent-issue floor of this loop; every structural escape measured worse.
__global__ __launch_bounds__(64)
__attribute__((amdgpu_waves_per_eu(1,1)))
void recur(const u16* __restrict__ gi,
    const u16* __restrict__ WhF, const u16* __restrict__ WhB,
    const u16* __restrict__ bhF, const u16* __restrict__ bhB,
    u16* __restrict__ y_x1, float* __restrict__ hfin, int layer)
{
  const int chain = blockIdx.x;
  const int dir = chain >> 7;
  const int b = chain & 127;
  const int j = threadIdx.x;           // lane 0..63
  const u16* Wh = dir ? WhB : WhF;
  const u16* bh = dir ? bhB : bhF;

  // this lane's three Whh rows as packed f16 pairs (bf16->f16 is exact)
  h2 wr[32], wz[32], wn[32];
  #pragma unroll
  for(int k8=0;k8<8;k8++){
    uint4 q;
    q = *(const uint4*)(Wh + (size_t)j*64 + k8*8);
    wr[4*k8+0] = (h2){bf2h((u16)(q.x&0xffffu)), bf2h((u16)(q.x>>16))};
    wr[4*k8+1] = (h2){bf2h((u16)(q.y&0xffffu)), bf2h((u16)(q.y>>16))};
    wr[4*k8+2] = (h2){bf2h((u16)(q.z&0xffffu)), bf2h((u16)(q.z>>16))};
    wr[4*k8+3] = (h2){bf2h((u16)(q.w&0xffffu)), bf2h((u16)(q.w>>16))};
    q = *(const uint4*)(Wh + (size_t)(64+j)*64 + k8*8);
    wz[4*k8+0] = (h2){bf2h((u16)(q.x&0xffffu)), bf2h((u16)(q.x>>16))};
    wz[4*k8+1] = (h2){bf2h((u16)(q.y&0xffffu)), bf2h((u16)(q.y>>16))};
    wz[4*k8+2] = (h2){bf2h((u16)(q.z&0xffffu)), bf2h((u16)(q.z>>16))};
    wz[4*k8+3] = (h2){bf2h((u16)(q.w&0xffffu)), bf2h((u16)(q.w>>16))};
    q = *(const uint4*)(Wh + (size_t)(128+j)*64 + k8*8);
    wn[4*k8+0] = (h2){bf2h((u16)(q.x&0xffffu)), bf2h((u16)(q.x>>16))};
    wn[4*k8+1] = (h2){bf2h((u16)(q.y&0xffffu)), bf2h((u16)(q.y>>16))};
    wn[4*k8+2] = (h2){bf2h((u16)(q.z&0xffffu)), bf2h((u16)(q.z>>16))};
    wn[4*k8+3] = (h2){bf2h((u16)(q.w&0xffffu)), bf2h((u16)(q.w>>16))};
  }
  const float bhr = bf2f(bh[j]), bhz = bf2f(bh[64+j]), bhn = bf2f(bh[128+j]);

  __shared__ __align__(16) u16 giLds[2][3072];   // 2 x 16 steps x 192 u16
  __shared__ _Float16 hSf[64];
  h8* hS8 = (h8*)hSf;
  hSf[j] = (_Float16)0.f;              // in-order DS: visible to the loop's reads

  const u16* giC = gi + (size_t)chain * T_ * G_;

  // async chunk DMA: 16 rows (6144 B) as 6 x (64 lanes x 16 B)
  auto issue_chunk = [&](int c, int buf){
    int tbase = dir ? (1008 - c*16) : (c*16);
    const u16* src = giC + (size_t)tbase*G_ + j*8;
    u16* dst = &giLds[buf][0];
    #pragma unroll
    for(int i=0;i<6;i++){
      __builtin_amdgcn_global_load_lds(
        (const __attribute__((address_space(1))) void*)(src + i*512),
        (__attribute__((address_space(3))) void*)(dst + i*512), 16, 0, 0);
    }
  };

  issue_chunk(0, 0);

  float h = 0.f;
  for(int c=0; c<64; ++c){
    asm volatile("s_waitcnt vmcnt(0)" ::: "memory");  // chunk c landed in LDS
    if (c < 63) issue_chunk(c+1, (c+1)&1);
    const u16* gbuf = &giLds[c&1][0];
    #pragma unroll 2
    for(int ls=0; ls<16; ++ls){
      int row = dir ? (15-ls) : ls;
      const u16* rowp = gbuf + row*G_;
      // matvec: 96 dot2 ops, 2 f32 accumulators per gate
      float r0=bhr, r1=0.f, z0=bhz, z1=0.f, n0=bhn, n1=0.f;
      #pragma unroll
      for(int k=0;k<8;k++){
        h8 hv = hS8[k];
        h2 p0 = __builtin_shufflevector(hv, hv, 0, 1);
        h2 p1 = __builtin_shufflevector(hv, hv, 2, 3);
        h2 p2 = __builtin_shufflevector(hv, hv, 4, 5);
        h2 p3 = __builtin_shufflevector(hv, hv, 6, 7);
        r0 = dot2(wr[4*k+0], p0, r0); r1 = dot2(wr[4*k+1], p1, r1);
        r0 = dot2(wr[4*k+2], p2, r0); r1 = dot2(wr[4*k+3], p3, r1);
        z0 = dot2(wz[4*k+0], p0, z0); z1 = dot2(wz[4*k+1], p1, z1);
        z0 = dot2(wz[4*k+2], p2, z0); z1 = dot2(wz[4*k+3], p3, z1);
        n0 = dot2(wn[4*k+0], p0, n0); n1 = dot2(wn[4*k+1], p1, n1);
        n0 = dot2(wn[4*k+2], p2, n0); n1 = dot2(wn[4*k+3], p3, n1);
      }
      float gr = bf2f(rowp[j]), gz = bf2f(rowp[64+j]), gn = bf2f(rowp[128+j]);

      float r  = sigm(gr + (r0+r1));
      float z  = sigm(gz + (z0+z1));
      float nn = tanh_(gn + r*(n0+n1));
      h = (1.f - z)*nn + z*h;

      hSf[j] = (_Float16)h;            // in-order DS; next iter's reads see it

      if (layer == 0){
        int s = c*16 + ls;
        int t = dir ? (T_-1-s) : s;
        y_x1[((size_t)b*T_ + t)*128 + dir*64 + j] = f2bf(h);
      }
    }
  }
  if (layer == 1) hfin[b*FUSED_ + dir*64 + j] = h;
}

// ---------------- fused static branch + qkv (gates stay in LDS) ----------------
__global__ __launch_bounds__(448) void staticqkv_k(const u16* __restrict__ sx,
   const u16* __restrict__ smW, const u16* __restrict__ smb,
   const u16* __restrict__ lng, const u16* __restrict__ lnb,
   const u16* __restrict__ gW, const u16* __restrict__ gb,
   const u16* __restrict__ phys, const u16* __restrict__ aW,
   const u16* __restrict__ ab,
   float* __restrict__ fused, float* __restrict__ qkv)
{
  int b = blockIdx.x, tid = threadIdx.x;
  __shared__ float gS[5];
  if (tid < 64){
    int j = tid;
    float xr[16];
    #pragma unroll
    for(int k=0;k<16;k++) xr[k] = bf2f(sx[b*16+k]);
    float acc = bf2f(smb[j]);
    #pragma unroll
    for(int k=0;k<16;k++) acc += xr[k]*bf2f(smW[j*16+k]);
    float xg = gelu_(acc);
    float m = wredsum(xg)*(1.f/64.f);
    float d = xg - m;
    float v = wredsum(d*d)*(1.f/64.f);
    float se = d*rsqrtf(v+1e-5f)*bf2f(lng[j]) + bf2f(lnb[j]);
    fused[b*FUSED_ + 128 + j] = se;
    #pragma unroll
    for(int i=0;i<5;i++){
      float p = se*bf2f(gW[i*64+j]);
      float s = wredsum(p);
      if (j == 0) gS[i] = sigm(s + bf2f(gb[i]));
    }
  }
  __syncthreads();
  int l = tid;
  if (l < PL_){
    float pv[5];
    #pragma unroll
    for(int i=0;i<5;i++) pv[i] = bf2f(phys[((size_t)b*5+i)*PL_ + l]) * gS[i];
    #pragma unroll
    for(int c=0;c<15;c++){
      float a = bf2f(ab[c]);
      #pragma unroll
      for(int i=0;i<5;i++) a += pv[i]*bf2f(aW[c*5+i]);
      qkv[((size_t)b*15+c)*PL_ + l] = a;
    }
  }
}

// ---------------- attention (rank-1 scores, softmax over j) ----------------
__global__ __launch_bounds__(256) void attn_k(const float* __restrict__ qkv,
                                              float* __restrict__ ao)
{
  int h = blockIdx.x, b = blockIdx.y;
  int tid = threadIdx.x;
  __shared__ float kS[PL_], vS[PL_];
  __shared__ float red[32];
  const float* qb = qkv + ((size_t)b*15 + h)*PL_;
  const float* kb = qkv + ((size_t)b*15 + 5 + h)*PL_;
  const float* vb = qkv + ((size_t)b*15 + 10 + h)*PL_;
  for(int j=tid;j<PL_;j+=256){ kS[j]=kb[j]; vS[j]=vb[j]; }
  __syncthreads();
  float lmax=-1e30f, lmin=1e30f;
  for(int j=tid;j<PL_;j+=256){ float kv=kS[j]; lmax=fmaxf(lmax,kv); lmin=fminf(lmin,kv); }
  #pragma unroll
  for(int o=32;o>0;o>>=1){ lmax=fmaxf(lmax,__shfl_xor(lmax,o)); lmin=fminf(lmin,__shfl_xor(lmin,o)); }
  int wv = tid>>6;
  if ((tid&63)==0){ red[wv]=lmax; red[8+wv]=lmin; }
  __syncthreads();
  if (tid==0){
    float mx=red[0], mn=red[8];
    for(int i=1;i<4;i++){ mx=fmaxf(mx,red[i]); mn=fminf(mn,red[8+i]); }
    red[16]=mx; red[17]=mn;
  }
  __syncthreads();
  float kmx=red[16], kmn=red[17];
  for(int i=tid;i<PL_;i+=256){
    float s = qb[i];
    float m = fmaxf(s*kmx, s*kmn);
    float den=0.f, num=0.f;
    #pragma unroll 4
    for(int j=0;j<PL_;j++){
      float e = __expf(s*kS[j]-m);
      den += e; num += e*vS[j];
    }
    ao[((size_t)b*PL_+i)*5 + h] = num/den;
  }
}

// ---------------- fused output projection + dilated convs (p2 stays in LDS) ----------------
template<int KS, int DIL, int PAD>
__device__ inline void do_conv(const float* pS, const u16* Wc, const u16* bc,
                               float* fused, int b, int o, int p, int cslot)
{
  const int Lout = PL_ + 2*PAD - DIL*(KS-1);
  float w[5][KS];
  #pragma unroll
  for(int i=0;i<5;i++)
    #pragma unroll
    for(int t=0;t<KS;t++) w[i][t] = bf2f(Wc[(o*5+i)*KS + t]);
  float bias = bf2f(bc[o]);
  float acc = 0.f;
  for(int l=p; l<Lout; l+=8){
    float s = bias;
    #pragma unroll
    for(int t=0;t<KS;t++){
      int idx = l - PAD + t*DIL;
      if (idx >= 0 && idx < PL_){
        #pragma unroll
        for(int i=0;i<5;i++) s += w[i][t]*pS[i*PL_ + idx];
      }
    }
    acc += gelu_(s);
  }
  #pragma unroll
  for(int off=1;off<8;off<<=1) acc += __shfl_xor(acc,off);
  if (p == 0) fused[b*FUSED_ + 192 + cslot*32 + o] = acc/(float)Lout;
}

__global__ __launch_bounds__(256) void projconv_k(const float* __restrict__ ao,
  const u16* __restrict__ oW, const u16* __restrict__ ob,
  const u16* __restrict__ W1c, const u16* __restrict__ b1c,
  const u16* __restrict__ W2c, const u16* __restrict__ b2c,
  const u16* __restrict__ W3c, const u16* __restrict__ b3c,
  float* __restrict__ fused)
{
  int b = blockIdx.x, tid = threadIdx.x;
  __shared__ float pS[5*PL_];
  for(int l=tid; l<PL_; l+=256){
    float a[5];
    #pragma unroll
    for(int hh=0;hh<5;hh++) a[hh] = ao[((size_t)b*PL_+l)*5 + hh];
    #pragma unroll
    for(int c=0;c<5;c++){
      float s = bf2f(ob[c]);
      #pragma unroll
      for(int hh=0;hh<5;hh++) s += a[hh]*bf2f(oW[c*5+hh]);
      pS[c*PL_ + l] = s;
    }
  }
  __syncthreads();
  int o = tid >> 3, p = tid & 7;
  do_conv<3,1,1>(pS, W1c, b1c, fused, b, o, p, 0);
  do_conv<5,2,2>(pS, W2c, b2c, fused, b, o, p, 1);
  do_conv<9,4,4>(pS, W3c, b3c, fused, b, o, p, 2);
}

// ---------------- head: LN + MLP (output dtype adaptive) ----------------
__global__ __launch_bounds__(448) void head_k(const float* __restrict__ fused,
   const u16* __restrict__ lng, const u16* __restrict__ lnb,
   const u16* __restrict__ W1, const u16* __restrict__ b1,
   const u16* __restrict__ W2, const u16* __restrict__ b2,
   void* __restrict__ out, const u16* __restrict__ detect)
{
  const bool isbf = (detect[0] == 0x3F80u);
  int b = blockIdx.x, tid = threadIdx.x;
  __shared__ float fS[FUSED_];
  __shared__ float hS[128];
  __shared__ float red[32];
  float v = (tid < FUSED_) ? fused[b*FUSED_ + tid] : 0.f;
  float s1 = wredsum(v);
  float s2 = wredsum(v*v);
  int wv = tid>>6;
  if ((tid&63)==0){ red[wv]=s1; red[8+wv]=s2; }
  __syncthreads();
  if (tid==0){
    float S=0.f, SS=0.f;
    for(int i=0;i<7;i++){ S+=red[i]; SS+=red[8+i]; }
    float m = S/288.f;
    red[16]=m; red[17]=SS/288.f - m*m;
  }
  __syncthreads();
  float m = red[16], var = red[17];
  if (tid < FUSED_) fS[tid] = (v-m)*rsqrtf(var+1e-5f)*bf2f(lng[tid]) + bf2f(lnb[tid]);
  __syncthreads();
  if (tid < 128){
    float a = bf2f(b1[tid]);
    const u16* wr = W1 + (size_t)tid*FUSED_;
    #pragma unroll
    for(int k8=0;k8<36;k8++){
      uint4 q = *(const uint4*)(wr + k8*8);
      a += fS[8*k8+0]*bf2f((u16)(q.x&0xffffu)) + fS[8*k8+1]*bf2f((u16)(q.x>>16))
         + fS[8*k8+2]*bf2f((u16)(q.y&0xffffu)) + fS[8*k8+3]*bf2f((u16)(q.y>>16))
         + fS[8*k8+4]*bf2f((u16)(q.z&0xffffu)) + fS[8*k8+5]*bf2f((u16)(q.z>>16))
         + fS[8*k8+6]*bf2f((u16)(q.w&0xffffu)) + fS[8*k8+7]*bf2f((u16)(q.w>>16));
    }
    hS[tid] = gelu_(a);
  }
  __syncthreads();
  if (tid < PL_){
    float a = bf2f(b2[tid]);
    const u16* wr = W2 + (size_t)tid*128;
    #pragma unroll
    for(int k8=0;k8<16;k8++){
      uint4 q = *(const uint4*)(wr + k8*8);
      a += hS[8*k8+0]*bf2f((u16)(q.x&0xffffu)) + hS[8*k8+1]*bf2f((u16)(q.x>>16))
         + hS[8*k8+2]*bf2f((u16)(q.y&0xffffu)) + hS[8*k8+3]*bf2f((u16)(q.y>>16))
         + hS[8*k8+4]*bf2f((u16)(q.z&0xffffu)) + hS[8*k8+5]*bf2f((u16)(q.z>>16))
         + hS[8*k8+6]*bf2f((u16)(q.w&0xffffu)) + hS[8*k8+7]*bf2f((u16)(q.w>>16));
    }
    size_t oi = (size_t)b*PL_ + tid;
    if (isbf) ((u16*)out)[oi] = f2bf(a);
    else      ((float*)out)[oi] = a;
  }
}

extern "C" void kernel_launch(void* const* d_in, const int* in_sizes, int n_in,
                              void* d_out, int out_size, void* d_ws, size_t ws_size,
                              hipStream_t stream)
{
  static const unsigned cnts[N_IN] = {
    4194304, 2048, 276480,
    6144, 12288, 192, 192,
    6144, 12288, 192, 192,
    24576, 12288, 192, 192,
    24576, 12288, 192, 192,
    1024, 64, 64, 64,
    320, 5,
    75, 15,
    25, 5,
    480, 32, 800, 32, 1440, 32,
    288, 288,
    36864, 128, 55296, 432
  };

  char* ws = (char*)d_ws;
  size_t off = 0;
  auto alloc = [&](size_t bytes){ size_t o = off; off = (off + bytes + 255) & ~(size_t)255; return o; };

  CvtArgs ca;
  const u16* cin[N_IN];
  unsigned totalBlocks = 0;
  for (int i=0;i<N_IN;i++){
    ca.src[i] = d_in[i];
    ca.cnt[i] = cnts[i];
    size_t o = alloc((size_t)cnts[i]*2);
    ca.dstOff[i] = (unsigned)(o/2);
    cin[i] = (const u16*)(ws + o);
    ca.blkStart[i] = totalBlocks;
    totalBlocks += (cnts[i] + 2047u)/2048u;
  }
  ca.blkStart[N_IN] = totalBlocks;
  u16* canon = (u16*)ws;

  u16*   gi    = (u16*)  (ws + alloc((size_t)2*BT_*G_*2));
  u16*   x1    = (u16*)  (ws + alloc((size_t)BT_*128*2));
  float* fused = (float*)(ws + alloc((size_t)B_*FUSED_*4));
  float* qkv   = (float*)(ws + alloc((size_t)B_*15*PL_*4));
  float* ao    = (float*)(ws + alloc((size_t)B_*PL_*5*4));
  (void)ws_size; (void)in_sizes; (void)n_in; (void)out_size;

  convert_k<<<totalBlocks, 256, 0, stream>>>(ca, canon);

  gi_gemm<32><<<BT_/64, 256, 0, stream>>>(cin[0], cin[3], cin[7], cin[5], cin[9], gi);
  recur<<<256, 64, 0, stream>>>(gi, cin[4], cin[8], cin[6], cin[10], x1, nullptr, 0);
  gi_gemm<128><<<BT_/64, 256, 0, stream>>>(x1, cin[11], cin[15], cin[13], cin[17], gi);
  recur<<<256, 64, 0, stream>>>(gi, cin[12], cin[16], cin[14], cin[18], nullptr, fused, 1);
  staticqkv_k<<<128, 448, 0, stream>>>(cin[1], cin[19], cin[20], cin[21], cin[22],
                                       cin[23], cin[24], cin[2], cin[25], cin[26],
                                       fused, qkv);
  attn_k<<<dim3(5,128), 256, 0, stream>>>(qkv, ao);
  projconv_k<<<128, 256, 0, stream>>>(ao, cin[27], cin[28], cin[29], cin[30],
                                      cin[31], cin[32], cin[33], cin[34], fused);
  head_k<<<128, 448, 0, stream>>>(fused, cin[35], cin[36], cin[37], cin[38], cin[39], cin[40],
                                  d_out, (const u16*)d_in[21]);
}